// Round 4
// baseline (76.599 us; speedup 1.0000x reference)
//
#include <hip/hip_runtime.h>
#include <hip/hip_bf16.h>

// Problem constants
#define NB 32      // batch
#define NC 8       // channels
#define NL 512     // length
#define NS 63      // scales
#define NK 1009    // max wavelet kernel length (odd)
#define NPAD 504   // (NK-1)/2
#define ND 512     // d_model
#define NCT 512    // total channels after concat = C*(1+S)
#define NROWS 514  // Apad rows per batch (circular-padded)

typedef __attribute__((ext_vector_type(4))) float f32x4;
typedef __attribute__((ext_vector_type(8))) short short8;
typedef __attribute__((ext_vector_type(4))) short short4v;

// Workspace layout (bytes)
#define APAD_BYTES (NB * NROWS * NL * 2)   // 16,842,752  bf16 [B][514][512]
#define WB_BYTES   (3 * ND * NL * 2)       //  1,572,864  bf16 [3][512][512]
#define BANKB_BYTES (64 * 1024 * 2)        //    131,072  bf16 [64][1024]

typedef const __attribute__((address_space(1))) unsigned int* gp1_t;
typedef __attribute__((address_space(3))) unsigned int* lp3_t;
__device__ __forceinline__ void gload_lds16(const void* g, void* l) {
  __builtin_amdgcn_global_load_lds((gp1_t)g, (lp3_t)l, 16, 0, 0);
}

__device__ __forceinline__ unsigned short bf16_bits(float v) {
  return __builtin_bit_cast(unsigned short, __float2bfloat16(v));
}

// ---------------------------------------------------------------------------
// Kernel 1: prep — Wb[k][o][l] = bf16(tw[o][l][k]) (coalesced single pass);
//           bankB[s][k] zero-padded bf16. (x->Apad moved into cwt.)
// ---------------------------------------------------------------------------
__global__ __launch_bounds__(256) void prep_kernel(
    const float* __restrict__ bank, const float* __restrict__ tw,
    __hip_bfloat16* __restrict__ Wb, __hip_bfloat16* __restrict__ bankB) {
  const int idx = blockIdx.x * 256 + threadIdx.x;
  const int stride = gridDim.x * 256;

  // Wb[k][i] = tw[i*3 + k], i = o*512 + l  (coalesced 12B read, 3 coalesced writes)
  for (int i = idx; i < ND * NL; i += stride) {
    float w0 = tw[i * 3 + 0];
    float w1 = tw[i * 3 + 1];
    float w2 = tw[i * 3 + 2];
    Wb[0 * ND * NL + i] = __float2bfloat16(w0);
    Wb[1 * ND * NL + i] = __float2bfloat16(w1);
    Wb[2 * ND * NL + i] = __float2bfloat16(w2);
  }
  for (int i = idx; i < 64 * 1024; i += stride) {
    int s = i >> 10;
    int k = i & 1023;
    float v = (s < NS && k < NK) ? bank[s * NK + k] : 0.f;
    bankB[i] = __float2bfloat16(v);
  }
}

// ---------------------------------------------------------------------------
// Kernel 2: cwt via MFMA (unchanged structure) + x->Apad copy folded in.
//   d[t][s] = | sum_k bank[s][k] * dx[t+k] |,  dx[i] = xpad[i+1]-xpad[i]
// ---------------------------------------------------------------------------
#define CPY_STRIDE 3088   // 1536*2 + 16 pad

__global__ __launch_bounds__(512) void cwt_kernel(
    const float* __restrict__ x, const __hip_bfloat16* __restrict__ bankB,
    __hip_bfloat16* __restrict__ Apad) {
  __shared__ char smem[32768 + 4 * CPY_STRIDE];
  char* bankS = smem;
  char* cpy = smem + 32768;

  const int tid = threadIdx.x;
  const int bc = blockIdx.x;
  const int b = bc >> 3, c = bc & 7;
  const int w = tid >> 6, l = tid & 63;
  const int hi = l >> 4, li = l & 15;

  const float* xrow = x + bc * NL;

  // x -> Apad row 1+c (and wrap row 513 from c==0)  [moved from prep]
  {
    __hip_bfloat16 v = __float2bfloat16(xrow[tid & 511]);
    if (tid < 512) {
      Apad[((size_t)(b * NROWS) + 1 + c) * NL + tid] = v;
      if (c == 0) Apad[((size_t)(b * NROWS) + 513) * NL + tid] = v;
    }
  }

  // stage dx copies: cpy[r][e] = bf16(dx[e+r]), e<1536, packed pair writes
  for (int i = 0; i < 6; ++i) {
    int p = tid + i * 512;
    int r = p / 768, pe = p - r * 768;
    int e0 = 2 * pe;
    int i0 = e0 + r;
    float xa = (i0 >= NPAD && i0 < NPAD + NL) ? xrow[i0 - NPAD] : 0.f;
    float xb = (i0 + 1 >= NPAD && i0 + 1 < NPAD + NL) ? xrow[i0 + 1 - NPAD] : 0.f;
    float xc = (i0 + 2 >= NPAD && i0 + 2 < NPAD + NL) ? xrow[i0 + 2 - NPAD] : 0.f;
    unsigned short u0 = bf16_bits(xb - xa);
    unsigned short u1 = bf16_bits(xc - xb);
    *(unsigned int*)(cpy + r * CPY_STRIDE + e0 * 2) = (unsigned)u0 | ((unsigned)u1 << 16);
  }

#define STAGE(kt, buf)                                                        \
  {                                                                           \
    for (int i = 0; i < 2; ++i) {                                             \
      int ck = tid + i * 512;                                                 \
      int s_ = ck >> 4, rb = ck & 15;                                         \
      int srcc = rb ^ (s_ & 7);                                               \
      gload_lds16(bankB + s_ * 1024 + (kt) * 128 + srcc * 8,                  \
                  bankS + (buf) * 16384 + ck * 16);                           \
    }                                                                         \
  }

  STAGE(0, 0);
  __syncthreads();

  f32x4 acc[4][4] = {};
  const int r = l & 3;
  const int tbase = w * 64;
  int buf = 0;

  for (int kt = 0; kt < 8; ++kt) {
    if (kt < 7) STAGE(kt + 1, buf ^ 1);

#pragma unroll
    for (int ksl = 0; ksl < 4; ++ksl) {
      short8 av[4], bv[4];
#pragma unroll
      for (int m = 0; m < 4; ++m) {
        int srow = m * 16 + li;
        int chunk = (ksl * 4 + hi) ^ (srow & 7);
        av[m] = *(const short8*)(bankS + buf * 16384 + srow * 256 + chunk * 16);
      }
#pragma unroll
      for (int n = 0; n < 4; ++n) {
        int t = tbase + n * 16 + li;
        int e = t - r + kt * 128 + ksl * 32 + hi * 8;
        const char* pc = cpy + r * CPY_STRIDE + e * 2;
        short4v lo = *(const short4v*)pc;
        short4v hh = *(const short4v*)(pc + 8);
        short8 f;
        f[0] = lo[0]; f[1] = lo[1]; f[2] = lo[2]; f[3] = lo[3];
        f[4] = hh[0]; f[5] = hh[1]; f[6] = hh[2]; f[7] = hh[3];
        bv[n] = f;
      }
#pragma unroll
      for (int m = 0; m < 4; ++m)
#pragma unroll
        for (int n = 0; n < 4; ++n)
          acc[m][n] = __builtin_amdgcn_mfma_f32_16x16x32_bf16(av[m], bv[n], acc[m][n], 0, 0, 0);
    }

    if (kt < 7) {
      __syncthreads();
      buf ^= 1;
    }
  }

  // epilogue: d = |acc| directly; lane holds D[s=m*16+hi*4+rg][t=w*64+n*16+li]
#pragma unroll
  for (int m = 0; m < 4; ++m) {
#pragma unroll
    for (int rg = 0; rg < 4; ++rg) {
      int s = m * 16 + hi * 4 + rg;
      if (s >= NS) continue;
      int ch = 8 + c * NS + s;
      size_t rowbase = ((size_t)(b * NROWS) + 1 + ch) * NL;
#pragma unroll
      for (int n = 0; n < 4; ++n) {
        int t = tbase + n * 16 + li;
        float d = fabsf(acc[m][n][rg]);
        __hip_bfloat16 hv = __float2bfloat16(d);
        bool lastgrp = (w == 7 && n == 3);
        bool skip = lastgrp && (li == 15);
        bool dup = lastgrp && (li == 14);
        if (!skip) Apad[rowbase + t] = hv;
        if (dup) Apad[rowbase + 511] = hv;
        if (ch == NCT - 1) {
          size_t wrapbase = (size_t)(b * NROWS) * NL;
          if (!skip) Apad[wrapbase + t] = hv;
          if (dup) Apad[wrapbase + 511] = hv;
        }
      }
    }
  }
#undef STAGE
}

// ---------------------------------------------------------------------------
// Kernel 3: gemm — out[b][p][o] = sum_{kap} sum_l Apad[b][p+kap][l]*Wb[kap][o][l]
// 128x128 tile, BK=32, mfma 16x16x32, NOW double-buffered (T3-minimum):
// STAGE(kk+1 -> buf^1) issued BEFORE compute(buf); one barrier per K-step.
// The barrier's vmcnt(0) drain lands after the MFMAs -> latency hidden.
// ---------------------------------------------------------------------------
__global__ __launch_bounds__(256) void gemm_kernel(
    const __hip_bfloat16* __restrict__ Ap, const __hip_bfloat16* __restrict__ Wb,
    float* __restrict__ out) {
  __shared__ __hip_bfloat16 sA[2][128 * 32];
  __shared__ __hip_bfloat16 sB[2][128 * 32];

  const int tid = threadIdx.x;
  const int b = blockIdx.y;
  const int tile = blockIdx.x;
  const int p0 = (tile & 3) * 128;
  const int o0 = (tile >> 2) * 128;

  const int w = tid >> 6, lane = tid & 63;
  const int wm = w >> 1, wn = w & 1;
  const int row_in = lane & 15, hi = lane >> 4;

  const int rA0 = tid >> 2, sg0 = tid & 3;
  const int rA1 = (tid + 256) >> 2, sg1 = (tid + 256) & 3;

#define GSTAGE(kk, bu)                                                            \
  {                                                                               \
    const int kap_ = (kk) >> 4;                                                   \
    const int l0_ = ((kk) & 15) << 5;                                             \
    gload_lds16(Ap + ((b * NROWS + p0 + kap_ + rA0) * NL + l0_ + sg0 * 8),        \
                &sA[bu][tid * 8]);                                                \
    gload_lds16(Ap + ((b * NROWS + p0 + kap_ + rA1) * NL + l0_ + sg1 * 8),        \
                &sA[bu][(tid + 256) * 8]);                                        \
    gload_lds16(Wb + ((kap_ * ND + o0 + rA0) * NL + l0_ + sg0 * 8),               \
                &sB[bu][tid * 8]);                                                \
    gload_lds16(Wb + ((kap_ * ND + o0 + rA1) * NL + l0_ + sg1 * 8),               \
                &sB[bu][(tid + 256) * 8]);                                        \
  }

  f32x4 acc[4][4] = {};

  GSTAGE(0, 0);
  __syncthreads();   // tile 0 resident

  int bu = 0;
  for (int kk = 0; kk < 48; ++kk) {
    if (kk < 47) GSTAGE(kk + 1, bu ^ 1);   // prefetch into other buffer

    short8 av[4], bv[4];
#pragma unroll
    for (int m = 0; m < 4; ++m)
      av[m] = *(const short8*)(&sA[bu][(wm * 64 + m * 16 + row_in) * 32 + hi * 8]);
#pragma unroll
    for (int n = 0; n < 4; ++n)
      bv[n] = *(const short8*)(&sB[bu][(wn * 64 + n * 16 + row_in) * 32 + hi * 8]);

#pragma unroll
    for (int m = 0; m < 4; ++m)
#pragma unroll
      for (int n = 0; n < 4; ++n)
        acc[m][n] = __builtin_amdgcn_mfma_f32_16x16x32_bf16(av[m], bv[n], acc[m][n], 0, 0, 0);

    __syncthreads();  // all reads of bu done; prefetched tile drained (vmcnt 0)
    bu ^= 1;
  }
#undef GSTAGE

#pragma unroll
  for (int m = 0; m < 4; ++m) {
    const int p = p0 + wm * 64 + m * 16 + hi * 4;
#pragma unroll
    for (int n = 0; n < 4; ++n) {
      const int o = o0 + wn * 64 + n * 16 + row_in;
#pragma unroll
      for (int r = 0; r < 4; ++r)
        out[(size_t)((b * NCT) + p + r) * ND + o] = acc[m][n][r];
    }
  }
}

// ---------------------------------------------------------------------------
extern "C" void kernel_launch(void* const* d_in, const int* in_sizes, int n_in,
                              void* d_out, int out_size, void* d_ws, size_t ws_size,
                              hipStream_t stream) {
  const float* x = (const float*)d_in[0];
  const float* bank = (const float*)d_in[1];
  const float* tw = (const float*)d_in[2];
  float* out = (float*)d_out;

  char* ws = (char*)d_ws;
  __hip_bfloat16* Apad = (__hip_bfloat16*)ws;
  __hip_bfloat16* Wb = (__hip_bfloat16*)(ws + APAD_BYTES);
  __hip_bfloat16* bankB = (__hip_bfloat16*)(ws + APAD_BYTES + WB_BYTES);

  prep_kernel<<<512, 256, 0, stream>>>(bank, tw, Wb, bankB);
  cwt_kernel<<<256, 512, 0, stream>>>(x, bankB, Apad);
  gemm_kernel<<<dim3(16, 32), 256, 0, stream>>>(Apad, Wb, out);
}

// Round 5
// 68.571 us; speedup vs baseline: 1.1171x; 1.1171x over previous
//
#include <hip/hip_runtime.h>
#include <hip/hip_bf16.h>

// Problem constants
#define NB 32      // batch
#define NC 8       // channels
#define NL 512     // length
#define NS 63      // scales
#define NK 1009    // max wavelet kernel length (odd)
#define NPAD 504   // (NK-1)/2
#define ND 512     // d_model
#define NCT 512    // total channels after concat = C*(1+S)
#define NROWS 514  // Apad rows per batch (circular-padded)

typedef __attribute__((ext_vector_type(4))) float f32x4;
typedef __attribute__((ext_vector_type(8))) short short8;
typedef __attribute__((ext_vector_type(4))) short short4v;

// Workspace layout (bytes)
#define APAD_BYTES (NB * NROWS * NL * 2)   // 16,842,752  bf16 [B][514][512]
#define WB_BYTES   (3 * ND * NL * 2)       //  1,572,864  bf16 [3][512][512]
#define BANKB_BYTES (64 * 1024 * 2)        //    131,072  bf16 [64][1024]

typedef const __attribute__((address_space(1))) unsigned int* gp1_t;
typedef __attribute__((address_space(3))) unsigned int* lp3_t;
__device__ __forceinline__ void gload_lds16(const void* g, void* l) {
  __builtin_amdgcn_global_load_lds((gp1_t)g, (lp3_t)l, 16, 0, 0);
}

__device__ __forceinline__ unsigned short bf16_bits(float v) {
  return __builtin_bit_cast(unsigned short, __float2bfloat16(v));
}

#define WAITVM(N) asm volatile("s_waitcnt vmcnt(" #N ")" ::: "memory")
#define FENCE() asm volatile("" ::: "memory")
#define BAR() __builtin_amdgcn_s_barrier()

// ---------------------------------------------------------------------------
// Kernel 1: prep — Wb[k][o][l] = bf16(tw[o][l][k]); bankB[s][k] zero-padded.
// ---------------------------------------------------------------------------
__global__ __launch_bounds__(256) void prep_kernel(
    const float* __restrict__ bank, const float* __restrict__ tw,
    __hip_bfloat16* __restrict__ Wb, __hip_bfloat16* __restrict__ bankB) {
  const int idx = blockIdx.x * 256 + threadIdx.x;
  const int stride = gridDim.x * 256;

  for (int i = idx; i < ND * NL; i += stride) {
    float w0 = tw[i * 3 + 0];
    float w1 = tw[i * 3 + 1];
    float w2 = tw[i * 3 + 2];
    Wb[0 * ND * NL + i] = __float2bfloat16(w0);
    Wb[1 * ND * NL + i] = __float2bfloat16(w1);
    Wb[2 * ND * NL + i] = __float2bfloat16(w2);
  }
  for (int i = idx; i < 64 * 1024; i += stride) {
    int s = i >> 10;
    int k = i & 1023;
    float v = (s < NS && k < NK) ? bank[s * NK + k] : 0.f;
    bankB[i] = __float2bfloat16(v);
  }
}

// ---------------------------------------------------------------------------
// Kernel 2: cwt via MFMA (unchanged from round 4 — passed at ~15 µs est.)
// ---------------------------------------------------------------------------
#define CPY_STRIDE 3088   // 1536*2 + 16 pad

__global__ __launch_bounds__(512) void cwt_kernel(
    const float* __restrict__ x, const __hip_bfloat16* __restrict__ bankB,
    __hip_bfloat16* __restrict__ Apad) {
  __shared__ char smem[32768 + 4 * CPY_STRIDE];
  char* bankS = smem;
  char* cpy = smem + 32768;

  const int tid = threadIdx.x;
  const int bc = blockIdx.x;
  const int b = bc >> 3, c = bc & 7;
  const int w = tid >> 6, l = tid & 63;
  const int hi = l >> 4, li = l & 15;

  const float* xrow = x + bc * NL;

  // x -> Apad row 1+c (and wrap row 513 from c==0)
  {
    __hip_bfloat16 v = __float2bfloat16(xrow[tid & 511]);
    if (tid < 512) {
      Apad[((size_t)(b * NROWS) + 1 + c) * NL + tid] = v;
      if (c == 0) Apad[((size_t)(b * NROWS) + 513) * NL + tid] = v;
    }
  }

  // stage dx copies: cpy[r][e] = bf16(dx[e+r]), e<1536
  for (int i = 0; i < 6; ++i) {
    int p = tid + i * 512;
    int r = p / 768, pe = p - r * 768;
    int e0 = 2 * pe;
    int i0 = e0 + r;
    float xa = (i0 >= NPAD && i0 < NPAD + NL) ? xrow[i0 - NPAD] : 0.f;
    float xb = (i0 + 1 >= NPAD && i0 + 1 < NPAD + NL) ? xrow[i0 + 1 - NPAD] : 0.f;
    float xc = (i0 + 2 >= NPAD && i0 + 2 < NPAD + NL) ? xrow[i0 + 2 - NPAD] : 0.f;
    unsigned short u0 = bf16_bits(xb - xa);
    unsigned short u1 = bf16_bits(xc - xb);
    *(unsigned int*)(cpy + r * CPY_STRIDE + e0 * 2) = (unsigned)u0 | ((unsigned)u1 << 16);
  }

#define STAGE(kt, buf)                                                        \
  {                                                                           \
    for (int i = 0; i < 2; ++i) {                                             \
      int ck = tid + i * 512;                                                 \
      int s_ = ck >> 4, rb = ck & 15;                                         \
      int srcc = rb ^ (s_ & 7);                                               \
      gload_lds16(bankB + s_ * 1024 + (kt) * 128 + srcc * 8,                  \
                  bankS + (buf) * 16384 + ck * 16);                           \
    }                                                                         \
  }

  STAGE(0, 0);
  __syncthreads();

  f32x4 acc[4][4] = {};
  const int r = l & 3;
  const int tbase = w * 64;
  int buf = 0;

  for (int kt = 0; kt < 8; ++kt) {
    if (kt < 7) STAGE(kt + 1, buf ^ 1);

#pragma unroll
    for (int ksl = 0; ksl < 4; ++ksl) {
      short8 av[4], bv[4];
#pragma unroll
      for (int m = 0; m < 4; ++m) {
        int srow = m * 16 + li;
        int chunk = (ksl * 4 + hi) ^ (srow & 7);
        av[m] = *(const short8*)(bankS + buf * 16384 + srow * 256 + chunk * 16);
      }
#pragma unroll
      for (int n = 0; n < 4; ++n) {
        int t = tbase + n * 16 + li;
        int e = t - r + kt * 128 + ksl * 32 + hi * 8;
        const char* pc = cpy + r * CPY_STRIDE + e * 2;
        short4v lo = *(const short4v*)pc;
        short4v hh = *(const short4v*)(pc + 8);
        short8 f;
        f[0] = lo[0]; f[1] = lo[1]; f[2] = lo[2]; f[3] = lo[3];
        f[4] = hh[0]; f[5] = hh[1]; f[6] = hh[2]; f[7] = hh[3];
        bv[n] = f;
      }
#pragma unroll
      for (int m = 0; m < 4; ++m)
#pragma unroll
        for (int n = 0; n < 4; ++n)
          acc[m][n] = __builtin_amdgcn_mfma_f32_16x16x32_bf16(av[m], bv[n], acc[m][n], 0, 0, 0);
    }

    if (kt < 7) {
      __syncthreads();
      buf ^= 1;
    }
  }

  // epilogue: d = |acc|; lane holds D[s=m*16+hi*4+rg][t=w*64+n*16+li]
#pragma unroll
  for (int m = 0; m < 4; ++m) {
#pragma unroll
    for (int rg = 0; rg < 4; ++rg) {
      int s = m * 16 + hi * 4 + rg;
      if (s >= NS) continue;
      int ch = 8 + c * NS + s;
      size_t rowbase = ((size_t)(b * NROWS) + 1 + ch) * NL;
#pragma unroll
      for (int n = 0; n < 4; ++n) {
        int t = tbase + n * 16 + li;
        float d = fabsf(acc[m][n][rg]);
        __hip_bfloat16 hv = __float2bfloat16(d);
        bool lastgrp = (w == 7 && n == 3);
        bool skip = lastgrp && (li == 15);
        bool dup = lastgrp && (li == 14);
        if (!skip) Apad[rowbase + t] = hv;
        if (dup) Apad[rowbase + 511] = hv;
        if (ch == NCT - 1) {
          size_t wrapbase = (size_t)(b * NROWS) * NL;
          if (!skip) Apad[wrapbase + t] = hv;
          if (dup) Apad[wrapbase + 511] = hv;
        }
      }
    }
  }
#undef STAGE
}

// ---------------------------------------------------------------------------
// Kernel 3: gemm — out[b][p][o] = sum_{kap} sum_l Apad[b][p+kap][l]*Wb[kap][o][l]
// 128x128 tile, BK=32, mfma 16x16x32.
// T4: triple-buffered, counted vmcnt(8) with raw s_barrier — prefetch loads
//     stay in flight across barriers; vmcnt never 0 until the tail.
// T2: LDS linear, global source chunk pre-swizzled cg = c ^ ((row>>1)&3);
//     reader applies the same XOR -> conflict-free b128 phase groups.
// ---------------------------------------------------------------------------
__global__ __launch_bounds__(256) void gemm_kernel(
    const __hip_bfloat16* __restrict__ Ap, const __hip_bfloat16* __restrict__ Wb,
    float* __restrict__ out) {
  __shared__ __hip_bfloat16 sA[3][128 * 32];
  __shared__ __hip_bfloat16 sB[3][128 * 32];

  const int tid = threadIdx.x;
  const int b = blockIdx.y;
  const int tile = blockIdx.x;
  const int p0 = (tile & 3) * 128;
  const int o0 = (tile >> 2) * 128;

  const int w = tid >> 6, lane = tid & 63;
  const int wm = w >> 1, wn = w & 1;
  const int row_in = lane & 15, hi = lane >> 4;

  // staging: LDS slot ck holds global chunk (row = ck>>2, cg = (ck&3)^((row>>1)&3))
  const int r0 = tid >> 2, cg0 = (tid & 3) ^ ((r0 >> 1) & 3);
  const int ck1 = tid + 256;
  const int r1 = ck1 >> 2, cg1 = (ck1 & 3) ^ ((r1 >> 1) & 3);

#define GSTAGE(kk, bu)                                                         \
  {                                                                            \
    const int kap_ = (kk) >> 4;                                                \
    const int l0_ = ((kk) & 15) << 5;                                          \
    gload_lds16(Ap + ((b * NROWS + p0 + kap_ + r0) * NL + l0_ + cg0 * 8),      \
                &sA[bu][tid * 8]);                                             \
    gload_lds16(Ap + ((b * NROWS + p0 + kap_ + r1) * NL + l0_ + cg1 * 8),      \
                &sA[bu][ck1 * 8]);                                             \
    gload_lds16(Wb + ((kap_ * ND + o0 + r0) * NL + l0_ + cg0 * 8),             \
                &sB[bu][tid * 8]);                                             \
    gload_lds16(Wb + ((kap_ * ND + o0 + r1) * NL + l0_ + cg1 * 8),             \
                &sB[bu][ck1 * 8]);                                             \
  }

#define COMPUTE(bu)                                                            \
  {                                                                            \
    short8 av[4], bv[4];                                                       \
    _Pragma("unroll") for (int m = 0; m < 4; ++m) {                            \
      int row = wm * 64 + m * 16 + row_in;                                     \
      int slot = row * 4 + (hi ^ ((row >> 1) & 3));                            \
      av[m] = *(const short8*)(&sA[bu][slot * 8]);                             \
    }                                                                          \
    _Pragma("unroll") for (int n = 0; n < 4; ++n) {                            \
      int row = wn * 64 + n * 16 + row_in;                                     \
      int slot = row * 4 + (hi ^ ((row >> 1) & 3));                            \
      bv[n] = *(const short8*)(&sB[bu][slot * 8]);                             \
    }                                                                          \
    _Pragma("unroll") for (int m = 0; m < 4; ++m)                              \
      _Pragma("unroll") for (int n = 0; n < 4; ++n)                            \
        acc[m][n] = __builtin_amdgcn_mfma_f32_16x16x32_bf16(av[m], bv[n],      \
                                                            acc[m][n], 0, 0, 0); \
  }

  f32x4 acc[4][4] = {};

  GSTAGE(0, 0);
  GSTAGE(1, 1);

  for (int g = 0; g < 15; ++g) {
    const int kk = g * 3;
    GSTAGE(kk + 2, 2); WAITVM(8); BAR(); FENCE(); COMPUTE(0); FENCE(); BAR();
    GSTAGE(kk + 3, 0); WAITVM(8); BAR(); FENCE(); COMPUTE(1); FENCE(); BAR();
    GSTAGE(kk + 4, 1); WAITVM(8); BAR(); FENCE(); COMPUTE(2); FENCE(); BAR();
  }
  // kk = 45, 46, 47 (tail: drain 8 -> 4 -> 0)
  GSTAGE(47, 2); WAITVM(8); BAR(); FENCE(); COMPUTE(0); FENCE(); BAR();
  WAITVM(4); BAR(); FENCE(); COMPUTE(1); FENCE(); BAR();
  WAITVM(0); BAR(); FENCE(); COMPUTE(2);
#undef GSTAGE
#undef COMPUTE

#pragma unroll
  for (int m = 0; m < 4; ++m) {
    const int p = p0 + wm * 64 + m * 16 + hi * 4;
#pragma unroll
    for (int n = 0; n < 4; ++n) {
      const int o = o0 + wn * 64 + n * 16 + row_in;
#pragma unroll
      for (int r = 0; r < 4; ++r)
        out[(size_t)((b * NCT) + p + r) * ND + o] = acc[m][n][r];
    }
  }
}

// ---------------------------------------------------------------------------
extern "C" void kernel_launch(void* const* d_in, const int* in_sizes, int n_in,
                              void* d_out, int out_size, void* d_ws, size_t ws_size,
                              hipStream_t stream) {
  const float* x = (const float*)d_in[0];
  const float* bank = (const float*)d_in[1];
  const float* tw = (const float*)d_in[2];
  float* out = (float*)d_out;

  char* ws = (char*)d_ws;
  __hip_bfloat16* Apad = (__hip_bfloat16*)ws;
  __hip_bfloat16* Wb = (__hip_bfloat16*)(ws + APAD_BYTES);
  __hip_bfloat16* bankB = (__hip_bfloat16*)(ws + APAD_BYTES + WB_BYTES);

  prep_kernel<<<512, 256, 0, stream>>>(bank, tw, Wb, bankB);
  cwt_kernel<<<256, 512, 0, stream>>>(x, bankB, Apad);
  gemm_kernel<<<dim3(16, 32), 256, 0, stream>>>(Apad, Wb, out);
}

// Round 6
// 62.742 us; speedup vs baseline: 1.2209x; 1.0929x over previous
//
#include <hip/hip_runtime.h>
#include <hip/hip_bf16.h>

// Problem constants
#define NB 32      // batch
#define NC 8       // channels
#define NL 512     // length
#define NS 63      // scales
#define NK 1009    // max wavelet kernel length (odd)
#define NPAD 504   // (NK-1)/2
#define ND 512     // d_model
#define NCT 512    // total channels after concat = C*(1+S)
#define NROWS 514  // Apad rows per batch (circular-padded)

typedef __attribute__((ext_vector_type(4))) float f32x4;
typedef __attribute__((ext_vector_type(8))) short short8;
typedef __attribute__((ext_vector_type(4))) short short4v;

// Workspace layout (bytes)
#define APAD_BYTES (NB * NROWS * NL * 2)   // 16,842,752  bf16 [B][514][512]
#define WB_BYTES   (3 * ND * NL * 2)       //  1,572,864  bf16 [3][512][512]
#define BANKB_BYTES (64 * 1024 * 2)        //    131,072  bf16 [64][1024]

typedef const __attribute__((address_space(1))) unsigned int* gp1_t;
typedef __attribute__((address_space(3))) unsigned int* lp3_t;
__device__ __forceinline__ void gload_lds16(const void* g, void* l) {
  __builtin_amdgcn_global_load_lds((gp1_t)g, (lp3_t)l, 16, 0, 0);
}

__device__ __forceinline__ unsigned short bf16_bits(float v) {
  return __builtin_bit_cast(unsigned short, __float2bfloat16(v));
}

#define WAITVM(N) asm volatile("s_waitcnt vmcnt(" #N ")" ::: "memory")
#define FENCE() asm volatile("" ::: "memory")
#define BAR() __builtin_amdgcn_s_barrier()

// ---------------------------------------------------------------------------
// Kernel 1: prep — Wb[k][o][l] = bf16(tw[o][l][k]); bankB[s][k] zero-padded.
// float4-vectorized: thread handles 4 consecutive i (12 floats = 3 float4).
// ---------------------------------------------------------------------------
__global__ __launch_bounds__(256) void prep_kernel(
    const float* __restrict__ bank, const float* __restrict__ tw,
    __hip_bfloat16* __restrict__ Wb, __hip_bfloat16* __restrict__ bankB) {
  const int idx = blockIdx.x * 256 + threadIdx.x;   // 65536 threads

  {
    int i0 = idx * 4;                  // 0..262140
    const float4* t4 = (const float4*)(tw + (size_t)i0 * 3);
    float4 a = t4[0], bq = t4[1], c4 = t4[2];
    ushort4 w0 = make_ushort4(bf16_bits(a.x), bf16_bits(a.w), bf16_bits(bq.z), bf16_bits(c4.y));
    ushort4 w1 = make_ushort4(bf16_bits(a.y), bf16_bits(bq.x), bf16_bits(bq.w), bf16_bits(c4.z));
    ushort4 w2 = make_ushort4(bf16_bits(a.z), bf16_bits(bq.y), bf16_bits(c4.x), bf16_bits(c4.w));
    *(ushort4*)(Wb + 0 * ND * NL + i0) = w0;
    *(ushort4*)(Wb + 1 * ND * NL + i0) = w1;
    *(ushort4*)(Wb + 2 * ND * NL + i0) = w2;
  }
  {
    int s = idx >> 10, k = idx & 1023;
    float v = (s < NS && k < NK) ? bank[s * NK + k] : 0.f;
    bankB[idx] = __float2bfloat16(v);
  }
}

// ---------------------------------------------------------------------------
// Kernel 2: cwt via MFMA.  d[t][s] = | sum_k bank[s][k] * dx[t+k] |.
// ALL 8 bank K-tiles staged upfront (128 KB LDS); per kt only a counted
// vmcnt + one barrier — full-depth DMA pipelining, no buffer hazards.
// ---------------------------------------------------------------------------
#define CPY_STRIDE 3088   // 1536*2 + 16 pad

__global__ __launch_bounds__(512) void cwt_kernel(
    const float* __restrict__ x, const __hip_bfloat16* __restrict__ bankB,
    __hip_bfloat16* __restrict__ Apad) {
  __shared__ char smem[8 * 16384 + 4 * CPY_STRIDE];  // 140 KB
  char* bankS = smem;
  char* cpy = smem + 8 * 16384;

  const int tid = threadIdx.x;
  const int bc = blockIdx.x;
  const int b = bc >> 3, c = bc & 7;
  const int w = tid >> 6, l = tid & 63;
  const int hi = l >> 4, li = l & 15;

  const float* xrow = x + bc * NL;

  // x -> Apad row 1+c (and wrap row 513 from c==0)
  if (tid < 512) {
    __hip_bfloat16 v = __float2bfloat16(xrow[tid]);
    Apad[((size_t)(b * NROWS) + 1 + c) * NL + tid] = v;
    if (c == 0) Apad[((size_t)(b * NROWS) + 513) * NL + tid] = v;
  }

  // stage dx copies: cpy[r][e] = bf16(dx[e+r]), e<1536 (issued BEFORE stages
  // so their vm ops are OLDEST — the counted waits below stay tile-accurate)
  for (int i = 0; i < 6; ++i) {
    int p = tid + i * 512;
    int r_ = p / 768, pe = p - r_ * 768;
    int e0 = 2 * pe;
    int i0 = e0 + r_;
    float xa = (i0 >= NPAD && i0 < NPAD + NL) ? xrow[i0 - NPAD] : 0.f;
    float xb = (i0 + 1 >= NPAD && i0 + 1 < NPAD + NL) ? xrow[i0 + 1 - NPAD] : 0.f;
    float xc = (i0 + 2 >= NPAD && i0 + 2 < NPAD + NL) ? xrow[i0 + 2 - NPAD] : 0.f;
    unsigned short u0 = bf16_bits(xb - xa);
    unsigned short u1 = bf16_bits(xc - xb);
    *(unsigned int*)(cpy + r_ * CPY_STRIDE + e0 * 2) = (unsigned)u0 | ((unsigned)u1 << 16);
  }

#define STAGE(kt)                                                             \
  {                                                                           \
    for (int i = 0; i < 2; ++i) {                                             \
      int ck = tid + i * 512;                                                 \
      int s_ = ck >> 4, rb = ck & 15;                                         \
      int srcc = rb ^ (s_ & 7);                                               \
      gload_lds16(bankB + s_ * 1024 + (kt) * 128 + srcc * 8,                  \
                  bankS + (kt) * 16384 + ck * 16);                            \
    }                                                                         \
  }

#define CCOMP(kt)                                                              \
  {                                                                            \
    _Pragma("unroll") for (int ksl = 0; ksl < 4; ++ksl) {                      \
      short8 av[4], bv[4];                                                     \
      _Pragma("unroll") for (int m = 0; m < 4; ++m) {                          \
        int srow = m * 16 + li;                                                \
        int chunk = (ksl * 4 + hi) ^ (srow & 7);                               \
        av[m] = *(const short8*)(bankS + (kt) * 16384 + srow * 256 + chunk * 16); \
      }                                                                        \
      _Pragma("unroll") for (int n = 0; n < 4; ++n) {                          \
        int t = tbase + n * 16 + li;                                           \
        int e = t - r + (kt) * 128 + ksl * 32 + hi * 8;                        \
        const char* pc = cpy + r * CPY_STRIDE + e * 2;                         \
        short4v lo = *(const short4v*)pc;                                      \
        short4v hh = *(const short4v*)(pc + 8);                                \
        short8 f;                                                              \
        f[0] = lo[0]; f[1] = lo[1]; f[2] = lo[2]; f[3] = lo[3];                \
        f[4] = hh[0]; f[5] = hh[1]; f[6] = hh[2]; f[7] = hh[3];                \
        bv[n] = f;                                                             \
      }                                                                        \
      _Pragma("unroll") for (int m = 0; m < 4; ++m)                            \
        _Pragma("unroll") for (int n = 0; n < 4; ++n)                          \
          acc[m][n] = __builtin_amdgcn_mfma_f32_16x16x32_bf16(av[m], bv[n],    \
                                                              acc[m][n], 0, 0, 0); \
    }                                                                          \
  }

  // issue ALL 8 tile stages (16 gload_lds in flight)
  STAGE(0); STAGE(1); STAGE(2); STAGE(3);
  STAGE(4); STAGE(5); STAGE(6); STAGE(7);

  f32x4 acc[4][4] = {};
  const int r = l & 3;
  const int tbase = w * 64;

  // tile kt ready when <= 14-2*kt vm ops outstanding (cpy ops are oldest,
  // so draining to N also drains them — conservative and correct)
  asm volatile("s_waitcnt vmcnt(14) lgkmcnt(0)" ::: "memory");
  BAR(); FENCE(); CCOMP(0);
  WAITVM(12); BAR(); FENCE(); CCOMP(1);
  WAITVM(10); BAR(); FENCE(); CCOMP(2);
  WAITVM(8);  BAR(); FENCE(); CCOMP(3);
  WAITVM(6);  BAR(); FENCE(); CCOMP(4);
  WAITVM(4);  BAR(); FENCE(); CCOMP(5);
  WAITVM(2);  BAR(); FENCE(); CCOMP(6);
  WAITVM(0);  BAR(); FENCE(); CCOMP(7);

  // epilogue: d = |acc|; lane holds D[s=m*16+hi*4+rg][t=w*64+n*16+li]
#pragma unroll
  for (int m = 0; m < 4; ++m) {
#pragma unroll
    for (int rg = 0; rg < 4; ++rg) {
      int s = m * 16 + hi * 4 + rg;
      if (s >= NS) continue;
      int ch = 8 + c * NS + s;
      size_t rowbase = ((size_t)(b * NROWS) + 1 + ch) * NL;
#pragma unroll
      for (int n = 0; n < 4; ++n) {
        int t = tbase + n * 16 + li;
        float d = fabsf(acc[m][n][rg]);
        __hip_bfloat16 hv = __float2bfloat16(d);
        bool lastgrp = (w == 7 && n == 3);
        bool skip = lastgrp && (li == 15);
        bool dup = lastgrp && (li == 14);
        if (!skip) Apad[rowbase + t] = hv;
        if (dup) Apad[rowbase + 511] = hv;
        if (ch == NCT - 1) {
          size_t wrapbase = (size_t)(b * NROWS) * NL;
          if (!skip) Apad[wrapbase + t] = hv;
          if (dup) Apad[wrapbase + 511] = hv;
        }
      }
    }
  }
#undef STAGE
#undef CCOMP
}

// ---------------------------------------------------------------------------
// Kernel 3: gemm — out[b][p][o] = sum_{kap} sum_l Apad[b][p+kap][l]*Wb[kap][o][l]
// 128x128 tile, BK=32, mfma 16x16x32.
// T1: XCD-chunked gid decode — 4 o-variants of (b,p) share gid%8 -> same XCD
//     L2 (4 batches x 0.53MB + Wb 1.5MB = 3.6MB < 4MB).
// T4: 4 LDS buffers, stage-2-ahead, vmcnt(8), ONE barrier per K-step
//     (stage target always >=1 barrier older than any reader).
// T2: source-swizzled chunks cg = c ^ ((row>>1)&3), reader same XOR.
// ---------------------------------------------------------------------------
__global__ __launch_bounds__(256) void gemm_kernel(
    const __hip_bfloat16* __restrict__ Ap, const __hip_bfloat16* __restrict__ Wb,
    float* __restrict__ out) {
  __shared__ __hip_bfloat16 sA[4][128 * 32];
  __shared__ __hip_bfloat16 sB[4][128 * 32];

  const int tid = threadIdx.x;
  // XCD-aware decode: gid%8 = XCD (round-robin dispatch assumption; perf-only)
  const int gid = blockIdx.x;          // 0..511
  const int q = gid >> 3;              // 0..63
  const int pid = (gid & 7) * 16 + (q >> 2);  // 0..127
  const int b = pid >> 2;
  const int p0 = (pid & 3) * 128;
  const int o0 = (q & 3) * 128;

  const int w = tid >> 6, lane = tid & 63;
  const int wm = w >> 1, wn = w & 1;
  const int row_in = lane & 15, hi = lane >> 4;

  const int r0 = tid >> 2, cg0 = (tid & 3) ^ ((r0 >> 1) & 3);
  const int ck1 = tid + 256;
  const int r1 = ck1 >> 2, cg1 = (ck1 & 3) ^ ((r1 >> 1) & 3);

#define GSTAGE(kk, bu)                                                         \
  {                                                                            \
    const int kap_ = (kk) >> 4;                                                \
    const int l0_ = ((kk) & 15) << 5;                                          \
    gload_lds16(Ap + ((b * NROWS + p0 + kap_ + r0) * NL + l0_ + cg0 * 8),      \
                &sA[bu][tid * 8]);                                             \
    gload_lds16(Ap + ((b * NROWS + p0 + kap_ + r1) * NL + l0_ + cg1 * 8),      \
                &sA[bu][ck1 * 8]);                                             \
    gload_lds16(Wb + ((kap_ * ND + o0 + r0) * NL + l0_ + cg0 * 8),             \
                &sB[bu][tid * 8]);                                             \
    gload_lds16(Wb + ((kap_ * ND + o0 + r1) * NL + l0_ + cg1 * 8),             \
                &sB[bu][ck1 * 8]);                                             \
  }

#define COMPUTE(bu)                                                            \
  {                                                                            \
    short8 av[4], bv[4];                                                       \
    _Pragma("unroll") for (int m = 0; m < 4; ++m) {                            \
      int row = wm * 64 + m * 16 + row_in;                                     \
      int slot = row * 4 + (hi ^ ((row >> 1) & 3));                            \
      av[m] = *(const short8*)(&sA[bu][slot * 8]);                             \
    }                                                                          \
    _Pragma("unroll") for (int n = 0; n < 4; ++n) {                            \
      int row = wn * 64 + n * 16 + row_in;                                     \
      int slot = row * 4 + (hi ^ ((row >> 1) & 3));                            \
      bv[n] = *(const short8*)(&sB[bu][slot * 8]);                             \
    }                                                                          \
    _Pragma("unroll") for (int m = 0; m < 4; ++m)                              \
      _Pragma("unroll") for (int n = 0; n < 4; ++n)                            \
        acc[m][n] = __builtin_amdgcn_mfma_f32_16x16x32_bf16(av[m], bv[n],      \
                                                            acc[m][n], 0, 0, 0); \
  }

  f32x4 acc[4][4] = {};

  GSTAGE(0, 0);
  GSTAGE(1, 1);

  for (int g = 0; g < 11; ++g) {
    const int kk = g * 4;
    GSTAGE(kk + 2, 2); WAITVM(8); BAR(); FENCE(); COMPUTE(0);
    GSTAGE(kk + 3, 3); WAITVM(8); BAR(); FENCE(); COMPUTE(1);
    GSTAGE(kk + 4, 0); WAITVM(8); BAR(); FENCE(); COMPUTE(2);
    GSTAGE(kk + 5, 1); WAITVM(8); BAR(); FENCE(); COMPUTE(3);
  }
  // tail: kk = 44..47
  GSTAGE(46, 2); WAITVM(8); BAR(); FENCE(); COMPUTE(0);
  GSTAGE(47, 3); WAITVM(8); BAR(); FENCE(); COMPUTE(1);
  WAITVM(4); BAR(); FENCE(); COMPUTE(2);
  WAITVM(0); BAR(); FENCE(); COMPUTE(3);
#undef GSTAGE
#undef COMPUTE

#pragma unroll
  for (int m = 0; m < 4; ++m) {
    const int p = p0 + wm * 64 + m * 16 + hi * 4;
#pragma unroll
    for (int n = 0; n < 4; ++n) {
      const int o = o0 + wn * 64 + n * 16 + row_in;
#pragma unroll
      for (int r = 0; r < 4; ++r)
        out[(size_t)((b * NCT) + p + r) * ND + o] = acc[m][n][r];
    }
  }
}

// ---------------------------------------------------------------------------
extern "C" void kernel_launch(void* const* d_in, const int* in_sizes, int n_in,
                              void* d_out, int out_size, void* d_ws, size_t ws_size,
                              hipStream_t stream) {
  const float* x = (const float*)d_in[0];
  const float* bank = (const float*)d_in[1];
  const float* tw = (const float*)d_in[2];
  float* out = (float*)d_out;

  char* ws = (char*)d_ws;
  __hip_bfloat16* Apad = (__hip_bfloat16*)ws;
  __hip_bfloat16* Wb = (__hip_bfloat16*)(ws + APAD_BYTES);
  __hip_bfloat16* bankB = (__hip_bfloat16*)(ws + APAD_BYTES + WB_BYTES);

  prep_kernel<<<256, 256, 0, stream>>>(bank, tw, Wb, bankB);
  cwt_kernel<<<256, 512, 0, stream>>>(x, bankB, Apad);
  gemm_kernel<<<512, 256, 0, stream>>>(Apad, Wb, out);
}

// Round 7
// 62.416 us; speedup vs baseline: 1.2272x; 1.0052x over previous
//
#include <hip/hip_runtime.h>
#include <hip/hip_bf16.h>

// Problem constants
#define NB 32      // batch
#define NC 8       // channels
#define NL 512     // length
#define NS 63      // scales
#define NK 1009    // max wavelet kernel length (odd)
#define NPAD 504   // (NK-1)/2
#define ND 512     // d_model
#define NCT 512    // total channels after concat = C*(1+S)
#define NROWS 514  // Apad rows per batch (circular-padded)

typedef __attribute__((ext_vector_type(4))) float f32x4;
typedef __attribute__((ext_vector_type(8))) short short8;
typedef __attribute__((ext_vector_type(4))) short short4v;

// Workspace layout (bytes)
#define APAD_BYTES (NB * NROWS * NL * 2)   // 16,842,752  bf16 [B][514][512]
#define WB_BYTES   (3 * ND * NL * 2)       //  1,572,864  bf16 [3][512][512]
#define BANKB_BYTES (64 * 1024 * 2)        //    131,072  bf16 [64][1024]

typedef const __attribute__((address_space(1))) unsigned int* gp1_t;
typedef __attribute__((address_space(3))) unsigned int* lp3_t;
__device__ __forceinline__ void gload_lds16(const void* g, void* l) {
  __builtin_amdgcn_global_load_lds((gp1_t)g, (lp3_t)l, 16, 0, 0);
}

__device__ __forceinline__ unsigned short bf16_bits(float v) {
  return __builtin_bit_cast(unsigned short, __float2bfloat16(v));
}

#define WAITVM(N) asm volatile("s_waitcnt vmcnt(" #N ")" ::: "memory")
#define FENCE() asm volatile("" ::: "memory")
#define BAR() __builtin_amdgcn_s_barrier()

// ---------------------------------------------------------------------------
// Kernel 1: prep — Wb[k][o][l] = bf16(tw[o][l][k]); bankB[s][k] zero-padded.
// ---------------------------------------------------------------------------
__global__ __launch_bounds__(256) void prep_kernel(
    const float* __restrict__ bank, const float* __restrict__ tw,
    __hip_bfloat16* __restrict__ Wb, __hip_bfloat16* __restrict__ bankB) {
  const int idx = blockIdx.x * 256 + threadIdx.x;   // 65536 threads

  {
    int i0 = idx * 4;
    const float4* t4 = (const float4*)(tw + (size_t)i0 * 3);
    float4 a = t4[0], bq = t4[1], c4 = t4[2];
    ushort4 w0 = make_ushort4(bf16_bits(a.x), bf16_bits(a.w), bf16_bits(bq.z), bf16_bits(c4.y));
    ushort4 w1 = make_ushort4(bf16_bits(a.y), bf16_bits(bq.x), bf16_bits(bq.w), bf16_bits(c4.z));
    ushort4 w2 = make_ushort4(bf16_bits(a.z), bf16_bits(bq.y), bf16_bits(c4.x), bf16_bits(c4.w));
    *(ushort4*)(Wb + 0 * ND * NL + i0) = w0;
    *(ushort4*)(Wb + 1 * ND * NL + i0) = w1;
    *(ushort4*)(Wb + 2 * ND * NL + i0) = w2;
  }
  {
    int s = idx >> 10, k = idx & 1023;
    float v = (s < NS && k < NK) ? bank[s * NK + k] : 0.f;
    bankB[idx] = __float2bfloat16(v);
  }
}

// ---------------------------------------------------------------------------
// Kernel 2: cwt via MFMA.  d[t][s] = | sum_k bank[s][k] * dx[t+k] |.
// Block = (bc, h): h=0 handles scale-blocks {0,3}, h=1 handles {1,2}
// (32 bank rows, 64KB tiles -> 77.9KB LDS -> 2 blocks/CU).
// Zero-tile skip: m0 kt2-4, m1 kt1-5, m2 kt0-6, m3 all (exact; bank rows
// are zero outside [504-8s, 504+8s]).
// ---------------------------------------------------------------------------
#define CPY_STRIDE 3088   // 1536*2 + 16 pad

__global__ __launch_bounds__(512) void cwt_kernel(
    const float* __restrict__ x, const __hip_bfloat16* __restrict__ bankB,
    __hip_bfloat16* __restrict__ Apad) {
  __shared__ char smem[8 * 8192 + 4 * CPY_STRIDE];  // 77,888 B
  char* bankS = smem;
  char* cpy = smem + 8 * 8192;

  const int tid = threadIdx.x;
  const int gid = blockIdx.x;
  const int bc = gid >> 1, h = gid & 1;
  const int b = bc >> 3, c = bc & 7;
  const int w = tid >> 6, l = tid & 63;
  const int hi = l >> 4, li = l & 15;
  const int ma = h ? 1 : 0, mb = h ? 2 : 3;   // scale-blocks handled

  const float* xrow = x + bc * NL;

  // x -> Apad row 1+c (and wrap row 513 from c==0); h==0 only (avoid dup)
  if (h == 0) {
    __hip_bfloat16 v = __float2bfloat16(xrow[tid & 511]);
    if (tid < 512) {
      Apad[((size_t)(b * NROWS) + 1 + c) * NL + tid] = v;
      if (c == 0) Apad[((size_t)(b * NROWS) + 513) * NL + tid] = v;
    }
  }

  // stage dx copies: cpy[r][e] = bf16(dx[e+r]), e<1536  (older than bank loads)
  for (int i = 0; i < 6; ++i) {
    int p = tid + i * 512;
    int r_ = p / 768, pe = p - r_ * 768;
    int e0 = 2 * pe;
    int i0 = e0 + r_;
    float xa = (i0 >= NPAD && i0 < NPAD + NL) ? xrow[i0 - NPAD] : 0.f;
    float xb = (i0 + 1 >= NPAD && i0 + 1 < NPAD + NL) ? xrow[i0 + 1 - NPAD] : 0.f;
    float xc = (i0 + 2 >= NPAD && i0 + 2 < NPAD + NL) ? xrow[i0 + 2 - NPAD] : 0.f;
    unsigned short u0 = bf16_bits(xb - xa);
    unsigned short u1 = bf16_bits(xc - xb);
    *(unsigned int*)(cpy + r_ * CPY_STRIDE + e0 * 2) = (unsigned)u0 | ((unsigned)u1 << 16);
  }

  // stage bank K-tile kt: 32 rows (ma's 16 then mb's 16), XOR-swizzled source
#define STAGE(kt)                                                             \
  {                                                                           \
    int s_ = tid >> 4, rb = tid & 15;                                         \
    int j = (s_ < 16) ? (ma * 16 + s_) : (mb * 16 + (s_ - 16));               \
    int srcc = rb ^ (s_ & 7);                                                 \
    gload_lds16(bankB + j * 1024 + (kt) * 128 + srcc * 8,                     \
                bankS + (kt) * 8192 + tid * 16);                              \
  }

  // compute tile kt; A0/A1 = activity of mm0 (rows ma) / mm1 (rows mb)
#define CCOMP(kt, A0, A1)                                                      \
  {                                                                            \
    _Pragma("unroll") for (int ksl = 0; ksl < 4; ++ksl) {                      \
      short8 bv[4];                                                            \
      _Pragma("unroll") for (int n = 0; n < 4; ++n) {                          \
        int t = tbase + n * 16 + li;                                           \
        int e = t - r + (kt) * 128 + ksl * 32 + hi * 8;                        \
        const char* pc = cpy + r * CPY_STRIDE + e * 2;                         \
        short4v lo = *(const short4v*)pc;                                      \
        short4v hh = *(const short4v*)(pc + 8);                                \
        short8 f;                                                              \
        f[0] = lo[0]; f[1] = lo[1]; f[2] = lo[2]; f[3] = lo[3];                \
        f[4] = hh[0]; f[5] = hh[1]; f[6] = hh[2]; f[7] = hh[3];                \
        bv[n] = f;                                                             \
      }                                                                        \
      if (A0) {                                                                \
        int lrow = li;                                                         \
        int chunk = (ksl * 4 + hi) ^ (lrow & 7);                               \
        short8 av = *(const short8*)(bankS + (kt) * 8192 + lrow * 256 + chunk * 16); \
        _Pragma("unroll") for (int n = 0; n < 4; ++n)                          \
          acc[0][n] = __builtin_amdgcn_mfma_f32_16x16x32_bf16(av, bv[n],       \
                                                              acc[0][n], 0, 0, 0); \
      }                                                                        \
      if (A1) {                                                                \
        int lrow = 16 + li;                                                    \
        int chunk = (ksl * 4 + hi) ^ (lrow & 7);                               \
        short8 av = *(const short8*)(bankS + (kt) * 8192 + lrow * 256 + chunk * 16); \
        _Pragma("unroll") for (int n = 0; n < 4; ++n)                          \
          acc[1][n] = __builtin_amdgcn_mfma_f32_16x16x32_bf16(av, bv[n],       \
                                                              acc[1][n], 0, 0, 0); \
      }                                                                        \
    }                                                                          \
  }

  f32x4 acc[2][4] = {};
  const int r = l & 3;
  const int tbase = w * 64;

  if (h == 0) {
    STAGE(0); STAGE(1); STAGE(2); STAGE(3);
    STAGE(4); STAGE(5); STAGE(6); STAGE(7);
    // masks: mm0=m0 active kt2-4; mm1=m3 active all
    asm volatile("s_waitcnt vmcnt(7) lgkmcnt(0)" ::: "memory");
    BAR(); FENCE(); CCOMP(0, 0, 1);
    WAITVM(6); BAR(); FENCE(); CCOMP(1, 0, 1);
    WAITVM(5); BAR(); FENCE(); CCOMP(2, 1, 1);
    WAITVM(4); BAR(); FENCE(); CCOMP(3, 1, 1);
    WAITVM(3); BAR(); FENCE(); CCOMP(4, 1, 1);
    WAITVM(2); BAR(); FENCE(); CCOMP(5, 0, 1);
    WAITVM(1); BAR(); FENCE(); CCOMP(6, 0, 1);
    WAITVM(0); BAR(); FENCE(); CCOMP(7, 0, 1);
  } else {
    STAGE(0); STAGE(1); STAGE(2); STAGE(3);
    STAGE(4); STAGE(5); STAGE(6);           // tile 7 unused by m1,m2
    // masks: mm0=m1 active kt1-5; mm1=m2 active kt0-6
    asm volatile("s_waitcnt vmcnt(6) lgkmcnt(0)" ::: "memory");
    BAR(); FENCE(); CCOMP(0, 0, 1);
    WAITVM(5); BAR(); FENCE(); CCOMP(1, 1, 1);
    WAITVM(4); BAR(); FENCE(); CCOMP(2, 1, 1);
    WAITVM(3); BAR(); FENCE(); CCOMP(3, 1, 1);
    WAITVM(2); BAR(); FENCE(); CCOMP(4, 1, 1);
    WAITVM(1); BAR(); FENCE(); CCOMP(5, 1, 1);
    WAITVM(0); BAR(); FENCE(); CCOMP(6, 0, 1);
  }

  // epilogue: d = |acc|; lane holds D[j][t], j = mblk*16 + hi*4 + rg,
  // t = w*64 + n*16 + li
#pragma unroll
  for (int mm = 0; mm < 2; ++mm) {
    const int mblk = mm ? mb : ma;
#pragma unroll
    for (int rg = 0; rg < 4; ++rg) {
      int jg = mblk * 16 + hi * 4 + rg;
      if (jg >= NS) continue;
      int ch = 8 + c * NS + jg;
      size_t rowbase = ((size_t)(b * NROWS) + 1 + ch) * NL;
#pragma unroll
      for (int n = 0; n < 4; ++n) {
        int t = tbase + n * 16 + li;
        float d = fabsf(acc[mm][n][rg]);
        __hip_bfloat16 hv = __float2bfloat16(d);
        bool lastgrp = (w == 7 && n == 3);
        bool skip = lastgrp && (li == 15);
        bool dup = lastgrp && (li == 14);
        if (!skip) Apad[rowbase + t] = hv;
        if (dup) Apad[rowbase + 511] = hv;
        if (ch == NCT - 1) {
          size_t wrapbase = (size_t)(b * NROWS) * NL;
          if (!skip) Apad[wrapbase + t] = hv;
          if (dup) Apad[wrapbase + 511] = hv;
        }
      }
    }
  }
#undef STAGE
#undef CCOMP
}

// ---------------------------------------------------------------------------
// Kernel 3: gemm, kap-folded.  out[b][p][o] = sum_kap sum_l A[p+kap][l]W[kap][o][l]
// 16 l-steps (BK=32): stage A-tile (128 rows) + 3 kap B-tiles per step,
// compute 48 MFMA/wave (3 kap x 16).  Boundary rows p0+128/129 preloaded
// once (full l) into a 2KB strip.  Double-buffered, counted vmcnt(8),
// two raw barriers/step.  T1 XCD decode + T2 source-swizzle retained.
// ---------------------------------------------------------------------------
__global__ __launch_bounds__(256) void gemm_kernel(
    const __hip_bfloat16* __restrict__ Ap, const __hip_bfloat16* __restrict__ Wb,
    float* __restrict__ out) {
  __shared__ char sAr[2 * 8192];        // [buf][128 rows x 32 l] bf16
  __shared__ char sBr[2 * 24576];       // [buf][3 kap][128 rows x 32 l]
  __shared__ char bnd[2048];            // rows p0+128, p0+129, full l
  __shared__ char dump[2048];           // scratch for uniform-issue preload

  const int tid = threadIdx.x;
  // T1: gid%8 = XCD; 4 o-variants of (b,p) share the XCD
  const int gid = blockIdx.x;          // 0..511
  const int q = gid >> 3;              // 0..63
  const int pid = (gid & 7) * 16 + (q >> 2);  // 0..127
  const int b = pid >> 2;
  const int p0 = (pid & 3) * 128;
  const int o0 = (q & 3) * 128;

  const int w = tid >> 6, lane = tid & 63;
  const int wm = w >> 1, wn = w & 1;
  const int row_in = lane & 15, hi = lane >> 4;

  const int rA0 = tid >> 2, cgA0 = (tid & 3) ^ ((rA0 >> 1) & 3);
  const int ck1 = tid + 256;
  const int rA1 = ck1 >> 2, cgA1 = (ck1 & 3) ^ ((rA1 >> 1) & 3);

  // boundary preload: waves 0,1 -> bnd rows 0,1; waves 2,3 -> dump (uniform)
  {
    int r_ = (tid >> 6) & 1;
    int col = tid & 63;
    const __hip_bfloat16* src =
        Ap + ((size_t)(b * NROWS) + p0 + 128 + r_) * NL + col * 8;
    char* dst = (tid < 128) ? (bnd + tid * 16) : (dump + (tid - 128) * 16);
    gload_lds16(src, dst);
  }

#define GSTAGE(kk, bu)                                                         \
  {                                                                            \
    const int l0_ = (kk) * 32;                                                 \
    gload_lds16(Ap + ((b * NROWS + p0 + rA0) * NL + l0_ + cgA0 * 8),           \
                sAr + (bu) * 8192 + tid * 16);                                 \
    gload_lds16(Ap + ((b * NROWS + p0 + rA1) * NL + l0_ + cgA1 * 8),           \
                sAr + (bu) * 8192 + ck1 * 16);                                 \
    _Pragma("unroll") for (int g = 0; g < 6; ++g) {                            \
      int id = g * 256 + tid;                                                  \
      int kap_ = id >> 9, ckb = id & 511;                                      \
      int row = ckb >> 2, cg = (ckb & 3) ^ ((row >> 1) & 3);                   \
      gload_lds16(Wb + ((kap_ * ND + o0 + row) * NL + l0_ + cg * 8),           \
                  sBr + (bu) * 24576 + id * 16);                               \
    }                                                                          \
  }

#define COMPUTE(bu, kk)                                                        \
  {                                                                            \
    const int l0_ = (kk) * 32;                                                 \
    _Pragma("unroll") for (int kap_ = 0; kap_ < 3; ++kap_) {                   \
      short8 av[4], bv[4];                                                     \
      _Pragma("unroll") for (int m = 0; m < 4; ++m) {                          \
        int arow = wm * 64 + m * 16 + row_in + kap_;                           \
        const char* pa;                                                        \
        if (m == 3) {                                                          \
          pa = (arow < 128)                                                    \
             ? (sAr + (bu) * 8192 + (arow * 4 + (hi ^ ((arow >> 1) & 3))) * 16)\
             : (bnd + (arow - 128) * 1024 + (l0_ + hi * 8) * 2);               \
        } else {                                                               \
          pa = sAr + (bu) * 8192 + (arow * 4 + (hi ^ ((arow >> 1) & 3))) * 16; \
        }                                                                      \
        av[m] = *(const short8*)pa;                                            \
      }                                                                        \
      _Pragma("unroll") for (int n = 0; n < 4; ++n) {                          \
        int brow = wn * 64 + n * 16 + row_in;                                  \
        bv[n] = *(const short8*)(sBr + (bu) * 24576 + kap_ * 8192 +            \
                                 (brow * 4 + (hi ^ ((brow >> 1) & 3))) * 16);  \
      }                                                                        \
      _Pragma("unroll") for (int m = 0; m < 4; ++m)                            \
        _Pragma("unroll") for (int n = 0; n < 4; ++n)                          \
          acc[m][n] = __builtin_amdgcn_mfma_f32_16x16x32_bf16(av[m], bv[n],    \
                                                              acc[m][n], 0, 0, 0); \
    }                                                                          \
  }

  f32x4 acc[4][4] = {};

  GSTAGE(0, 0);                        // + bnd already issued (9 outstanding)

  for (int kk = 0; kk < 15; ++kk) {
    GSTAGE(kk + 1, (kk + 1) & 1);      // prefetch next l-tile
    WAITVM(8);                         // drain tile kk (+ bnd on first iter)
    BAR(); FENCE();
    COMPUTE(kk & 1, kk);
    FENCE(); BAR();                    // readers done before next overwrite
  }
  WAITVM(0); BAR(); FENCE();
  COMPUTE(1, 15);
#undef GSTAGE
#undef COMPUTE

#pragma unroll
  for (int m = 0; m < 4; ++m) {
    const int p = p0 + wm * 64 + m * 16 + hi * 4;
#pragma unroll
    for (int n = 0; n < 4; ++n) {
      const int o = o0 + wn * 64 + n * 16 + row_in;
#pragma unroll
      for (int r = 0; r < 4; ++r)
        out[(size_t)((b * NCT) + p + r) * ND + o] = acc[m][n][r];
    }
  }
}

// ---------------------------------------------------------------------------
extern "C" void kernel_launch(void* const* d_in, const int* in_sizes, int n_in,
                              void* d_out, int out_size, void* d_ws, size_t ws_size,
                              hipStream_t stream) {
  const float* x = (const float*)d_in[0];
  const float* bank = (const float*)d_in[1];
  const float* tw = (const float*)d_in[2];
  float* out = (float*)d_out;

  char* ws = (char*)d_ws;
  __hip_bfloat16* Apad = (__hip_bfloat16*)ws;
  __hip_bfloat16* Wb = (__hip_bfloat16*)(ws + APAD_BYTES);
  __hip_bfloat16* bankB = (__hip_bfloat16*)(ws + APAD_BYTES + WB_BYTES);

  prep_kernel<<<256, 256, 0, stream>>>(bank, tw, Wb, bankB);
  cwt_kernel<<<512, 512, 0, stream>>>(x, bankB, Apad);
  gemm_kernel<<<512, 256, 0, stream>>>(Apad, Wb, out);
}